// Round 1
// baseline (5473.307 us; speedup 1.0000x reference)
//
#include <hip/hip_runtime.h>
#include <math.h>

#define K 20
#define KP1 21
#define F 32
#define NNODES 1000000

// pair counts per side at each level
#define NP1 112896   // 5376*21
#define NP2 5376     // 256*21
#define NP3 256

__device__ __forceinline__ int nhash(int node, int j) {
    // (node*101 + (j+1)*7919) % 1e6 ; fits in int32 (max ~1.01e8)
    return (node * 101 + (j + 1) * 7919) % NNODES;
}

template<int LEVEL>
__global__ __launch_bounds__(256) void attn_kernel(
    const int* __restrict__ src_idx, const int* __restrict__ tgt_idx,
    const float* __restrict__ cut_time,
    const float* __restrict__ emb,
    const float* __restrict__ freq, const float* __restrict__ phase,
    const float* __restrict__ Wq_, const float* __restrict__ Wk_,
    const float* __restrict__ Wv_, const float* __restrict__ Wo_,
    const float* __restrict__ mw1_, const float* __restrict__ mb1_,
    const float* __restrict__ mw2_, const float* __restrict__ mb2_,
    const float* __restrict__ h_in,
    float* __restrict__ h_out)
{
    constexpr int NPAIRS = (LEVEL == 1) ? NP1 : (LEVEL == 2 ? NP2 : NP3);
    constexpr int PREVN  = (LEVEL == 2) ? NP1 : NP2;  // only used for LEVEL>=2
    constexpr int l = LEVEL - 1;

    __shared__ float kin[4][K][68];   // padded rows: 272B, 16B aligned
    __shared__ float qin[4][64];
    __shared__ float xbuf[4][96];
    __shared__ float hbuf[4][32];

    const int tid  = threadIdx.x;
    const int w    = tid >> 6;
    const int lane = tid & 63;
    const int wid  = blockIdx.x * 4 + w;
    const int side = (wid >= NPAIRS) ? 1 : 0;
    const int p    = wid - side * NPAIRS;

    // ---- derive (node, time) for this pair from the roots
    int b, s2 = 0, r = 0;
    if (LEVEL == 3)      { b = p; }
    else if (LEVEL == 2) { b = p / KP1; s2 = p % KP1; }
    else                 { int q = p / KP1; r = p % KP1; b = q / KP1; s2 = q % KP1; }

    const int   root = side ? tgt_idx[b] : src_idx[b];
    const float ct   = cut_time[b];

    int nodeA; float tA;
    if (LEVEL == 3) { nodeA = root; tA = ct; }
    else if (LEVEL == 2) {
        nodeA = s2 ? nhash(root, s2 - 1) : root;
        tA    = s2 ? ct * ((float)s2 / 21.0f) : ct;
    } else {
        const int   node2 = s2 ? nhash(root, s2 - 1) : root;
        const float t2    = s2 ? ct * ((float)s2 / 21.0f) : ct;
        nodeA = r ? nhash(node2, r - 1) : node2;
        tA    = r ? t2 * ((float)r / 21.0f) : t2;
    }

    const float* Wq  = Wq_  + l * 64 * 64;
    const float* Wk  = Wk_  + l * 64 * 64;
    const float* Wv  = Wv_  + l * 64 * 64;
    const float* Wo  = Wo_  + l * 64 * 64;
    const float* mw1 = mw1_ + l * 96 * 32;
    const float* mb1 = mb1_ + l * 32;
    const float* mw2 = mw2_ + l * 32 * 32;
    const float* mb2 = mb2_ + l * 32;

    const float fr = (lane >= 32) ? freq[lane - 32]  : 0.0f;
    const float ph = (lane >= 32) ? phase[lane - 32] : 0.0f;

    // ---- fill q_in = [src_feat || cos(0*freq+phase)]
    float qv;
    if (lane < 32) {
        if (LEVEL == 1) qv = emb[(size_t)nodeA * F + lane];
        else            qv = h_in[((size_t)side * PREVN + (size_t)p * KP1) * F + lane];
    } else {
        qv = cosf(ph);
    }
    qin[w][lane] = qv;

    // ---- fill k_in rows + mask bits (wave-uniform)
    unsigned maskbits = 0;
    #pragma unroll
    for (int j = 0; j < K; ++j) {
        const int ngh = nhash(nodeA, j);
        if (ngh == 0) maskbits |= (1u << j);
        const float ngh_t = tA * ((float)(j + 1) / 21.0f);
        const float delta = tA - ngh_t;
        float v;
        if (lane < 32) {
            if (LEVEL == 1) v = emb[(size_t)ngh * F + lane];
            else            v = h_in[((size_t)side * PREVN + (size_t)p * KP1 + 1 + j) * F + lane];
        } else {
            v = cosf(delta * fr + ph);
        }
        kin[w][j][lane] = v;
    }
    __syncthreads();

    // ---- projections: lane d holds q[d], k[j][d], v[j][d]
    float qd = 0.0f;
    float kc[K], vc[K];
    #pragma unroll
    for (int j = 0; j < K; ++j) { kc[j] = 0.0f; vc[j] = 0.0f; }

    for (int e4 = 0; e4 < 16; ++e4) {
        const float4 q4 = *(reinterpret_cast<const float4*>(&qin[w][0]) + e4);
        const int e = e4 * 4;
        qd += q4.x * Wq[(e+0)*64+lane] + q4.y * Wq[(e+1)*64+lane]
            + q4.z * Wq[(e+2)*64+lane] + q4.w * Wq[(e+3)*64+lane];
    }
    for (int e4 = 0; e4 < 16; ++e4) {
        const int e = e4 * 4;
        const float wk0 = Wk[(e+0)*64+lane], wk1 = Wk[(e+1)*64+lane],
                    wk2 = Wk[(e+2)*64+lane], wk3 = Wk[(e+3)*64+lane];
        const float wv0 = Wv[(e+0)*64+lane], wv1 = Wv[(e+1)*64+lane],
                    wv2 = Wv[(e+2)*64+lane], wv3 = Wv[(e+3)*64+lane];
        #pragma unroll
        for (int j = 0; j < K; ++j) {
            const float4 t = *(reinterpret_cast<const float4*>(&kin[w][j][0]) + e4);
            kc[j] += t.x*wk0 + t.y*wk1 + t.z*wk2 + t.w*wk3;
            vc[j] += t.x*wv0 + t.y*wv1 + t.z*wv2 + t.w*wv3;
        }
    }

    // ---- scores: reduce over 16-lane head group; softmax in-register
    float sc[K];
    #pragma unroll
    for (int j = 0; j < K; ++j) {
        float s = qd * kc[j];
        #pragma unroll
        for (int off = 1; off < 16; off <<= 1) s += __shfl_xor(s, off, 16);
        s *= 0.25f;                       // 1/sqrt(HEAD_DIM=16)
        if ((maskbits >> j) & 1) s = -1e9f;
        sc[j] = s;
    }
    float m = sc[0];
    #pragma unroll
    for (int j = 1; j < K; ++j) m = fmaxf(m, sc[j]);
    float sum = 0.0f;
    #pragma unroll
    for (int j = 0; j < K; ++j) { sc[j] = __expf(sc[j] - m); sum += sc[j]; }
    const float inv = 1.0f / sum;

    float od = 0.0f;
    #pragma unroll
    for (int j = 0; j < K; ++j) od += sc[j] * vc[j];
    od *= inv;

    // ---- Wo projection
    xbuf[w][lane] = od;
    __syncthreads();
    float o2 = 0.0f;
    for (int e4 = 0; e4 < 16; ++e4) {
        const float4 t = *(reinterpret_cast<const float4*>(&xbuf[w][0]) + e4);
        const int e = e4 * 4;
        o2 += t.x * Wo[(e+0)*64+lane] + t.y * Wo[(e+1)*64+lane]
            + t.z * Wo[(e+2)*64+lane] + t.w * Wo[(e+3)*64+lane];
    }
    __syncthreads();

    // ---- MergeLayer MLP: x = [out@Wo (64) || src_feat (32)]
    xbuf[w][lane] = o2;
    if (lane < 32) xbuf[w][64 + lane] = qin[w][lane];
    __syncthreads();

    if (lane < 32) {
        float hv = mb1[lane];
        for (int e4 = 0; e4 < 24; ++e4) {
            const float4 t = *(reinterpret_cast<const float4*>(&xbuf[w][0]) + e4);
            const int e = e4 * 4;
            hv += t.x * mw1[(e+0)*32+lane] + t.y * mw1[(e+1)*32+lane]
                + t.z * mw1[(e+2)*32+lane] + t.w * mw1[(e+3)*32+lane];
        }
        hbuf[w][lane] = fmaxf(hv, 0.0f);
    }
    __syncthreads();
    if (lane < 32) {
        float y = mb2[lane];
        for (int e4 = 0; e4 < 8; ++e4) {
            const float4 t = *(reinterpret_cast<const float4*>(&hbuf[w][0]) + e4);
            const int e = e4 * 4;
            y += t.x * mw2[(e+0)*32+lane] + t.y * mw2[(e+1)*32+lane]
               + t.z * mw2[(e+2)*32+lane] + t.w * mw2[(e+3)*32+lane];
        }
        h_out[((size_t)side * NPAIRS + p) * F + lane] = y;
    }
}

__global__ __launch_bounds__(256) void final_kernel(
    const float* __restrict__ h3,
    const float* __restrict__ aw1, const float* __restrict__ ab1,
    const float* __restrict__ aw2, const float* __restrict__ ab2,
    float* __restrict__ out)
{
    const int bidx = threadIdx.x;   // 256 threads, 1 block
    float x[64];
    #pragma unroll
    for (int e = 0; e < 32; ++e) {
        x[e]      = h3[(size_t)bidx * 32 + e];            // src embed
        x[32 + e] = h3[((size_t)NP3 + bidx) * 32 + e];    // tgt embed
    }
    float acc = ab2[0];
    for (int f = 0; f < 32; ++f) {
        float hv = ab1[f];
        #pragma unroll
        for (int e = 0; e < 64; ++e) hv += x[e] * aw1[e * 32 + f];
        acc += fmaxf(hv, 0.0f) * aw2[f];
    }
    out[bidx] = acc;
}

extern "C" void kernel_launch(void* const* d_in, const int* in_sizes, int n_in,
                              void* d_out, int out_size, void* d_ws, size_t ws_size,
                              hipStream_t stream)
{
    const int*   src_idx = (const int*)d_in[0];
    const int*   tgt_idx = (const int*)d_in[1];
    const float* cut     = (const float*)d_in[2];
    // d_in[3] = num_neighbors (20), compile-time constant here
    const float* emb   = (const float*)d_in[4];
    const float* freq  = (const float*)d_in[5];
    const float* phase = (const float*)d_in[6];
    const float* Wq    = (const float*)d_in[7];
    const float* Wk    = (const float*)d_in[8];
    const float* Wv    = (const float*)d_in[9];
    const float* Wo    = (const float*)d_in[10];
    const float* mw1   = (const float*)d_in[11];
    const float* mb1   = (const float*)d_in[12];
    const float* mw2   = (const float*)d_in[13];
    const float* mb2   = (const float*)d_in[14];
    const float* aw1   = (const float*)d_in[15];
    const float* ab1   = (const float*)d_in[16];
    const float* aw2   = (const float*)d_in[17];
    const float* ab2   = (const float*)d_in[18];

    float* h1 = (float*)d_ws;                          // 2*NP1*32 floats
    float* h2 = h1 + (size_t)2 * NP1 * F;              // 2*NP2*32
    float* h3 = h2 + (size_t)2 * NP2 * F;              // 2*NP3*32

    const dim3 blk(256);
    attn_kernel<1><<<dim3(2 * NP1 / 4), blk, 0, stream>>>(
        src_idx, tgt_idx, cut, emb, freq, phase,
        Wq, Wk, Wv, Wo, mw1, mb1, mw2, mb2, (const float*)nullptr, h1);
    attn_kernel<2><<<dim3(2 * NP2 / 4), blk, 0, stream>>>(
        src_idx, tgt_idx, cut, emb, freq, phase,
        Wq, Wk, Wv, Wo, mw1, mb1, mw2, mb2, h1, h2);
    attn_kernel<3><<<dim3(2 * NP3 / 4), blk, 0, stream>>>(
        src_idx, tgt_idx, cut, emb, freq, phase,
        Wq, Wk, Wv, Wo, mw1, mb1, mw2, mb2, h2, h3);
    final_kernel<<<dim3(1), blk, 0, stream>>>(h3, aw1, ab1, aw2, ab2, (float*)d_out);
}

// Round 2
// 2101.332 us; speedup vs baseline: 2.6047x; 2.6047x over previous
//
#include <hip/hip_runtime.h>
#include <math.h>

#define K 20
#define KP1 21
#define F 32
#define NNODES 1000000

#define NP1 112896   // 5376*21
#define NP2 5376     // 256*21
#define NP3 256

// ws float offsets
#define OFF_WQT  0
#define OFF_WVT  12288
#define OFF_WOT  24576
#define OFF_MW1T 36864
#define OFF_MW2T 46080
#define OFF_H1   49152
#define OFF_H2   (OFF_H1 + 2 * NP1 * F)
#define OFF_H3   (OFF_H2 + 2 * NP2 * F)

__device__ __forceinline__ int nhash(int node, int j) {
    return (node * 101 + (j + 1) * 7919) % NNODES;   // max ~1.01e8, fits int32
}

__global__ __launch_bounds__(256) void transpose_weights(
    const float* __restrict__ Wq, const float* __restrict__ Wv,
    const float* __restrict__ Wo, const float* __restrict__ mw1,
    const float* __restrict__ mw2, float* __restrict__ ws)
{
    const int l = blockIdx.x;            // 0..2
    const int tid = threadIdx.x;
    float* wqt  = ws + OFF_WQT  + l * 4096;
    float* wvt  = ws + OFF_WVT  + l * 4096;
    float* wot  = ws + OFF_WOT  + l * 4096;
    float* mw1t = ws + OFF_MW1T + l * 3072;
    float* mw2t = ws + OFF_MW2T + l * 1024;
    for (int i = tid; i < 4096; i += 256) {
        int d = i >> 6, e = i & 63;
        wqt[d * 64 + e] = Wq[l * 4096 + e * 64 + d];
        wvt[d * 64 + e] = Wv[l * 4096 + e * 64 + d];
        wot[d * 64 + e] = Wo[l * 4096 + e * 64 + d];
    }
    for (int i = tid; i < 3072; i += 256) {
        int d = i / 96, e = i % 96;
        mw1t[d * 96 + e] = mw1[l * 3072 + e * 32 + d];
    }
    for (int i = tid; i < 1024; i += 256) {
        int d = i >> 5, e = i & 31;
        mw2t[d * 32 + e] = mw2[l * 1024 + e * 32 + d];
    }
}

template<int LEVEL>
__global__ __launch_bounds__(256) void attn_kernel(
    const int* __restrict__ src_idx, const int* __restrict__ tgt_idx,
    const float* __restrict__ cut_time,
    const float* __restrict__ emb,
    const float* __restrict__ freq, const float* __restrict__ phase,
    const float* __restrict__ Wk_,     // original row-major [l][e][d]
    const float* __restrict__ WqT_, const float* __restrict__ WvT_,
    const float* __restrict__ WoT_,
    const float* __restrict__ mw1T_, const float* __restrict__ mb1_,
    const float* __restrict__ mw2T_, const float* __restrict__ mb2_,
    const float* __restrict__ h_in,
    float* __restrict__ h_out)
{
    constexpr int NPAIRS = (LEVEL == 1) ? NP1 : (LEVEL == 2 ? NP2 : NP3);
    constexpr int PREVN  = (LEVEL == 2) ? NP1 : NP2;
    constexpr int l = LEVEL - 1;

    __shared__ float kin[4][K][64];
    __shared__ float qin[4][64];
    __shared__ float qz[4][4][68];    // qk_h[e], then reused for z_h[e] (padded)
    __shared__ float xbuf[4][96];     // qd, then attn-out, then merge input
    __shared__ float hbuf[4][32];

    const int tid  = threadIdx.x;
    const int w    = tid >> 6;
    const int lane = tid & 63;
    const int h    = lane >> 4;
    const int c    = lane & 15;
    const int wid  = blockIdx.x * 4 + w;
    const int side = (wid >= NPAIRS) ? 1 : 0;
    const int p    = wid - side * NPAIRS;

    // ---- derive (node, time) for this pair (bit-identical to round-1 kernel)
    int b, s2 = 0, r = 0;
    if (LEVEL == 3)      { b = p; }
    else if (LEVEL == 2) { b = p / KP1; s2 = p % KP1; }
    else                 { int q = p / KP1; r = p % KP1; b = q / KP1; s2 = q % KP1; }

    const int   root = side ? tgt_idx[b] : src_idx[b];
    const float ct   = cut_time[b];

    int nodeA; float tA;
    if (LEVEL == 3) { nodeA = root; tA = ct; }
    else if (LEVEL == 2) {
        nodeA = s2 ? nhash(root, s2 - 1) : root;
        tA    = s2 ? ct * ((float)s2 / 21.0f) : ct;
    } else {
        const int   node2 = s2 ? nhash(root, s2 - 1) : root;
        const float t2    = s2 ? ct * ((float)s2 / 21.0f) : ct;
        nodeA = r ? nhash(node2, r - 1) : node2;
        tA    = r ? t2 * ((float)r / 21.0f) : t2;
    }

    const float* Wk   = Wk_   + l * 4096;
    const float* WqT  = WqT_  + l * 4096;
    const float* WvT  = WvT_  + l * 4096;
    const float* WoT  = WoT_  + l * 4096;
    const float* mw1T = mw1T_ + l * 3072;
    const float* mb1  = mb1_  + l * 32;
    const float* mw2T = mw2T_ + l * 1024;
    const float* mb2  = mb2_  + l * 32;

    // ---- mask bits (all lanes, wave-uniform)
    unsigned maskbits = 0;
    #pragma unroll
    for (int j = 0; j < K; ++j)
        if (nhash(nodeA, j) == 0) maskbits |= (1u << j);

    // ---- feature fill (vectorized)
    if (LEVEL == 1) {
        if (lane < 8) {
            float4 v = *(const float4*)&emb[(size_t)nodeA * F + lane * 4];
            *(float4*)&qin[w][lane * 4] = v;
        }
        #pragma unroll
        for (int it = 0; it < 3; ++it) {
            int idx4 = it * 64 + lane;
            if (idx4 < 160) {
                int j = idx4 >> 3, c4 = idx4 & 7;
                int ngh = nhash(nodeA, j);
                float4 v = *(const float4*)&emb[(size_t)ngh * F + c4 * 4];
                *(float4*)&kin[w][j][c4 * 4] = v;
            }
        }
    } else {
        const float* base = h_in + ((size_t)side * PREVN + (size_t)p * KP1) * F;
        #pragma unroll
        for (int it = 0; it < 3; ++it) {
            int idx4 = it * 64 + lane;
            if (idx4 < 168) {
                int row = idx4 >> 3, c4 = idx4 & 7;
                float4 v = *(const float4*)&base[row * F + c4 * 4];
                if (row == 0) *(float4*)&qin[w][c4 * 4] = v;
                else          *(float4*)&kin[w][row - 1][c4 * 4] = v;
            }
        }
    }

    // ---- time encodings spread over all 64 lanes (math identical to round 1)
    {
        const int td = lane & 31;
        const float fr = freq[td], ph = phase[td];
        if (lane >= 32) qin[w][32 + td] = cosf(ph);
        #pragma unroll
        for (int it = 0; it < 10; ++it) {
            int j = it * 2 + (lane >> 5);
            float ngh_t = tA * ((float)(j + 1) / 21.0f);
            float delta = tA - ngh_t;
            kin[w][j][32 + td] = cosf(delta * fr + ph);
        }
    }

    // ---- q projection: qd[lane]
    float qd = 0.0f;
    #pragma unroll
    for (int e4 = 0; e4 < 16; ++e4) {
        float4 x = *(float4*)&qin[w][e4 * 4];
        float4 wv = *(const float4*)&WqT[lane * 64 + e4 * 4];
        qd += x.x * wv.x + x.y * wv.y + x.z * wv.z + x.w * wv.w;
    }
    xbuf[w][lane] = qd;

    // ---- qk_h[e] = sum_{d in head h} qd[d] * Wk[e][d]   (lane = e)
    {
        float qkacc[4] = {0.f, 0.f, 0.f, 0.f};
        #pragma unroll
        for (int hh = 0; hh < 4; ++hh) {
            #pragma unroll
            for (int c4 = 0; c4 < 4; ++c4) {
                float4 q4 = *(float4*)&xbuf[w][hh * 16 + c4 * 4];
                float4 k4 = *(const float4*)&Wk[lane * 64 + hh * 16 + c4 * 4];
                qkacc[hh] += q4.x * k4.x + q4.y * k4.y + q4.z * k4.z + q4.w * k4.w;
            }
        }
        #pragma unroll
        for (int hh = 0; hh < 4; ++hh) qz[w][hh][lane] = qkacc[hh];
    }

    // ---- scores: lane (h,c) covers e = 4c..4c+3, butterfly over 16 lanes
    float4 myqk = *(float4*)&qz[w][h][c * 4];
    float sc[K];
    #pragma unroll
    for (int j = 0; j < K; ++j) {
        float4 kk = *(float4*)&kin[w][j][c * 4];
        sc[j] = myqk.x * kk.x + myqk.y * kk.y + myqk.z * kk.z + myqk.w * kk.w;
    }
    #pragma unroll
    for (int off = 1; off < 16; off <<= 1) {
        #pragma unroll
        for (int j = 0; j < K; ++j) sc[j] += __shfl_xor(sc[j], off, 16);
    }
    #pragma unroll
    for (int j = 0; j < K; ++j) {
        float s = sc[j] * 0.25f;                 // 1/sqrt(16)
        if ((maskbits >> j) & 1) s = -1e9f;
        sc[j] = s;
    }

    // ---- softmax (in-register, replicated in all lanes)
    float m = sc[0];
    #pragma unroll
    for (int j = 1; j < K; ++j) m = fmaxf(m, sc[j]);
    float sum = 0.0f;
    #pragma unroll
    for (int j = 0; j < K; ++j) { sc[j] = __expf(sc[j] - m); sum += sc[j]; }
    const float inv = 1.0f / sum;

    // ---- z_h[e] = sum_j attn_h[j] * kin[j][e]  (same lane->e mapping)
    {
        float zx = 0.f, zy = 0.f, zz = 0.f, zw = 0.f;
        #pragma unroll
        for (int j = 0; j < K; ++j) {
            float4 kk = *(float4*)&kin[w][j][c * 4];
            zx += sc[j] * kk.x; zy += sc[j] * kk.y;
            zz += sc[j] * kk.z; zw += sc[j] * kk.w;
        }
        float4 z4; z4.x = zx * inv; z4.y = zy * inv; z4.z = zz * inv; z4.w = zw * inv;
        *(float4*)&qz[w][h][c * 4] = z4;          // overwrite qk (already consumed)
    }

    // ---- attn out: od[d] = sum_e z_h(d)[e] * Wv[e][d]
    float od = 0.0f;
    #pragma unroll
    for (int e4 = 0; e4 < 16; ++e4) {
        float4 z = *(float4*)&qz[w][h][e4 * 4];
        float4 wv4 = *(const float4*)&WvT[lane * 64 + e4 * 4];
        od += z.x * wv4.x + z.y * wv4.y + z.z * wv4.z + z.w * wv4.w;
    }
    xbuf[w][lane] = od;

    // ---- Wo projection
    float o2 = 0.0f;
    #pragma unroll
    for (int e4 = 0; e4 < 16; ++e4) {
        float4 x = *(float4*)&xbuf[w][e4 * 4];
        float4 wo4 = *(const float4*)&WoT[lane * 64 + e4 * 4];
        o2 += x.x * wo4.x + x.y * wo4.y + x.z * wo4.z + x.w * wo4.w;
    }
    xbuf[w][lane] = o2;
    if (lane < 32) xbuf[w][64 + lane] = qin[w][lane];

    // ---- MergeLayer MLP, all 64 lanes (split e-range, shfl-combine)
    const int dd = lane & 31;
    const int half = lane >> 5;
    float hv = 0.0f;
    #pragma unroll
    for (int e4 = 0; e4 < 12; ++e4) {
        float4 x = *(float4*)&xbuf[w][half * 48 + e4 * 4];
        float4 w4 = *(const float4*)&mw1T[dd * 96 + half * 48 + e4 * 4];
        hv += x.x * w4.x + x.y * w4.y + x.z * w4.z + x.w * w4.w;
    }
    hv += __shfl_xor(hv, 32);
    hv = fmaxf(hv + mb1[dd], 0.0f);
    if (lane < 32) hbuf[w][dd] = hv;

    float y = 0.0f;
    #pragma unroll
    for (int e4 = 0; e4 < 4; ++e4) {
        float4 x = *(float4*)&hbuf[w][half * 16 + e4 * 4];
        float4 w4 = *(const float4*)&mw2T[dd * 32 + half * 16 + e4 * 4];
        y += x.x * w4.x + x.y * w4.y + x.z * w4.z + x.w * w4.w;
    }
    y += __shfl_xor(y, 32);
    if (lane < 32)
        h_out[((size_t)side * NPAIRS + p) * F + dd] = y + mb2[dd];
}

__global__ __launch_bounds__(256) void final_kernel(
    const float* __restrict__ h3,
    const float* __restrict__ aw1, const float* __restrict__ ab1,
    const float* __restrict__ aw2, const float* __restrict__ ab2,
    float* __restrict__ out)
{
    const int bidx = threadIdx.x;   // 256 threads, 1 block
    float x[64];
    #pragma unroll
    for (int e = 0; e < 32; ++e) {
        x[e]      = h3[(size_t)bidx * 32 + e];
        x[32 + e] = h3[((size_t)NP3 + bidx) * 32 + e];
    }
    float acc = ab2[0];
    for (int f = 0; f < 32; ++f) {
        float hv = ab1[f];
        #pragma unroll
        for (int e = 0; e < 64; ++e) hv += x[e] * aw1[e * 32 + f];
        acc += fmaxf(hv, 0.0f) * aw2[f];
    }
    out[bidx] = acc;
}

extern "C" void kernel_launch(void* const* d_in, const int* in_sizes, int n_in,
                              void* d_out, int out_size, void* d_ws, size_t ws_size,
                              hipStream_t stream)
{
    const int*   src_idx = (const int*)d_in[0];
    const int*   tgt_idx = (const int*)d_in[1];
    const float* cut     = (const float*)d_in[2];
    const float* emb   = (const float*)d_in[4];
    const float* freq  = (const float*)d_in[5];
    const float* phase = (const float*)d_in[6];
    const float* Wq    = (const float*)d_in[7];
    const float* Wk    = (const float*)d_in[8];
    const float* Wv    = (const float*)d_in[9];
    const float* Wo    = (const float*)d_in[10];
    const float* mw1   = (const float*)d_in[11];
    const float* mb1   = (const float*)d_in[12];
    const float* mw2   = (const float*)d_in[13];
    const float* mb2   = (const float*)d_in[14];
    const float* aw1   = (const float*)d_in[15];
    const float* ab1   = (const float*)d_in[16];
    const float* aw2   = (const float*)d_in[17];
    const float* ab2   = (const float*)d_in[18];

    float* ws = (float*)d_ws;
    const float* WqT  = ws + OFF_WQT;
    const float* WvT  = ws + OFF_WVT;
    const float* WoT  = ws + OFF_WOT;
    const float* mw1T = ws + OFF_MW1T;
    const float* mw2T = ws + OFF_MW2T;
    float* h1 = ws + OFF_H1;
    float* h2 = ws + OFF_H2;
    float* h3 = ws + OFF_H3;

    const dim3 blk(256);
    transpose_weights<<<dim3(3), blk, 0, stream>>>(Wq, Wv, Wo, mw1, mw2, ws);
    attn_kernel<1><<<dim3(2 * NP1 / 4), blk, 0, stream>>>(
        src_idx, tgt_idx, cut, emb, freq, phase,
        Wk, WqT, WvT, WoT, mw1T, mb1, mw2T, mb2, (const float*)nullptr, h1);
    attn_kernel<2><<<dim3(2 * NP2 / 4), blk, 0, stream>>>(
        src_idx, tgt_idx, cut, emb, freq, phase,
        Wk, WqT, WvT, WoT, mw1T, mb1, mw2T, mb2, h1, h2);
    attn_kernel<3><<<dim3(2 * NP3 / 4), blk, 0, stream>>>(
        src_idx, tgt_idx, cut, emb, freq, phase,
        Wk, WqT, WvT, WoT, mw1T, mb1, mw2T, mb2, h2, h3);
    final_kernel<<<dim3(1), blk, 0, stream>>>(h3, aw1, ab1, aw2, ab2, (float*)d_out);
}